// Round 1
// baseline (440.900 us; speedup 1.0000x reference)
//
#include <hip/hip_runtime.h>
#include <hip/hip_bf16.h>

#define IMG 224
#define NPS 14       // patches per side
#define NP  196
#define BATCH 64
#define PD  3840     // patch dim = 16*16*15
#define PROJ 768
#define M_TOT (BATCH*NP)        // 12544
#define TOK_SIZE (M_TOT*PROJ)   // 9633792

typedef __attribute__((ext_vector_type(8))) __bf16 bf16x8;
typedef __attribute__((ext_vector_type(4))) float f32x4;

__device__ __forceinline__ unsigned short f2bf(float f) {
    unsigned int u = __builtin_bit_cast(unsigned int, f);
    u += 0x7FFFu + ((u >> 16) & 1u);
    return (unsigned short)(u >> 16);
}

// ---------------- prep: gather patches + per-row mean/rstd ----------------
__global__ __launch_bounds__(256) void prep_kernel(
    const float* __restrict__ images, float* __restrict__ patches_out,
    float2* __restrict__ mr) {
  const int pid = blockIdx.x;            // 0..12543
  const int b  = pid / NP;
  const int pp = pid - b*NP;
  const int ph = pp / NPS;
  const int pw = pp - ph*NPS;
  const int t = threadIdx.x;

  float s = 0.f, s2 = 0.f;
  #pragma unroll
  for (int r = 0; r < 15; ++r) {
    int d   = t + r*256;
    int ch5 = d % 15;
    int rem = d / 15;
    int q = rem & 15;
    int p = rem >> 4;
    int g = ch5 / 3;
    int c = ch5 - g*3;
    // shift offsets: g0:(0,0) g1:(+8,+8) g2:(-8,+8) g3:(+8,-8) g4:(-8,-8)
    int dh = (g==0) ? 0 : ((g & 1) ? 8 : -8);
    int dw = (g==0) ? 0 : ((g <= 2) ? 8 : -8);
    int ii = ph*16 + p + dh;
    int jj = pw*16 + q + dw;
    float v = 0.f;
    if ((unsigned)ii < IMG && (unsigned)jj < IMG)
      v = images[((b*IMG + ii)*IMG + jj)*3 + c];
    s += v; s2 += v*v;
    patches_out[(size_t)pid*PD + d] = v;
  }
  // wave64 butterfly reduce then cross-wave via LDS
  #pragma unroll
  for (int o = 32; o > 0; o >>= 1) { s += __shfl_xor(s, o); s2 += __shfl_xor(s2, o); }
  __shared__ float red[8];
  int w = t >> 6;
  if ((t & 63) == 0) { red[w*2] = s; red[w*2+1] = s2; }
  __syncthreads();
  if (t == 0) {
    float S  = red[0]+red[2]+red[4]+red[6];
    float S2 = red[1]+red[3]+red[5]+red[7];
    float mean = S * (1.f/PD);
    float var  = S2 * (1.f/PD) - mean*mean;
    float rstd = rsqrtf(var + 1e-6f);
    mr[pid] = make_float2(mean, rstd);
  }
}

// ---------------- W transpose: (3840x768 f32) -> (768x3840 bf16) ----------
__global__ __launch_bounds__(256) void wtrans_kernel(
    const float* __restrict__ W, unsigned short* __restrict__ Wt) {
  __shared__ float tile[32][33];
  const int bx = blockIdx.x;   // n-tile 0..23
  const int by = blockIdx.y;   // k-tile 0..119
  const int tx = threadIdx.x;  // 0..31
  const int ty = threadIdx.y;  // 0..7
  #pragma unroll
  for (int r = 0; r < 4; ++r) {
    int k = by*32 + ty + r*8;
    int n = bx*32 + tx;
    tile[ty + r*8][tx] = W[k*PROJ + n];
  }
  __syncthreads();
  #pragma unroll
  for (int r = 0; r < 4; ++r) {
    int n = bx*32 + ty + r*8;
    int k = by*32 + tx;
    Wt[(size_t)n*PD + k] = f2bf(tile[tx][ty + r*8]);
  }
}

// ---------------- GEMM: tokens = LN(patches) @ W + b, bf16 MFMA -----------
__global__ __launch_bounds__(256) void gemm_kernel(
    const float* __restrict__ patches,      // [M_TOT][PD] f32
    const float2* __restrict__ mr,          // mean, rstd per row
    const float* __restrict__ gamma,
    const float* __restrict__ beta,
    const unsigned short* __restrict__ Wt,  // [PROJ][PD] bf16 bits
    const float* __restrict__ bias,
    float* __restrict__ tokens) {
  __shared__ unsigned short Alds[128][40];  // pad to 40 (20 banks) -> 2-way max
  const int bn = blockIdx.x;   // 0..5   (fastest: same-bm blocks adjacent)
  const int bm = blockIdx.y;   // 0..97
  const int t = threadIdx.x;
  const int l = t & 63;
  const int w = t >> 6;
  const int wr = w >> 1, wc = w & 1;
  const int m0 = bm * 128;
  const int n0 = bn * 128;

  const int lrow = l & 15;      // A-row / B-col within fragment
  const int lk   = l >> 4;      // k-group

  // B fragment pointers (Wt row-major N x K: contiguous 16B per lane)
  const unsigned short* bp[4];
  #pragma unroll
  for (int fc = 0; fc < 4; ++fc) {
    int n = n0 + wc*64 + fc*16 + lrow;
    bp[fc] = Wt + (size_t)n * PD + lk*8;
  }

  const int srow = t >> 3;        // 0..31 (row within 32-row staging pass)
  const int skq  = (t & 7) * 4;   // k quad 0,4,..,28

  f32x4 acc[4][4];
  #pragma unroll
  for (int i = 0; i < 4; ++i)
    #pragma unroll
    for (int j = 0; j < 4; ++j) acc[i][j] = f32x4{0.f, 0.f, 0.f, 0.f};

  bf16x8 bfrag[4], bnext[4];
  #pragma unroll
  for (int fc = 0; fc < 4; ++fc)
    bfrag[fc] = *reinterpret_cast<const bf16x8*>(bp[fc]);

  for (int kt = 0; kt < 120; ++kt) {
    const int k0 = kt * 32;
    // stage A tile 128x32 with fused LayerNorm, f32 -> bf16
    #pragma unroll
    for (int pass = 0; pass < 4; ++pass) {
      int row = pass*32 + srow;
      int m = m0 + row;
      float2 mrv = mr[m];
      const float4 v  = *reinterpret_cast<const float4*>(patches + (size_t)m*PD + k0 + skq);
      const float4 gv = *reinterpret_cast<const float4*>(gamma + k0 + skq);
      const float4 bv = *reinterpret_cast<const float4*>(beta  + k0 + skq);
      ushort4 o;
      o.x = f2bf((v.x - mrv.x)*mrv.y*gv.x + bv.x);
      o.y = f2bf((v.y - mrv.x)*mrv.y*gv.y + bv.y);
      o.z = f2bf((v.z - mrv.x)*mrv.y*gv.z + bv.z);
      o.w = f2bf((v.w - mrv.x)*mrv.y*gv.w + bv.w);
      *reinterpret_cast<ushort4*>(&Alds[row][skq]) = o;
    }
    // register-prefetch next B fragments (hides latency across the barrier)
    if (kt < 119) {
      #pragma unroll
      for (int fc = 0; fc < 4; ++fc)
        bnext[fc] = *reinterpret_cast<const bf16x8*>(bp[fc] + k0 + 32);
    }
    __syncthreads();
    bf16x8 afrag[4];
    #pragma unroll
    for (int fr = 0; fr < 4; ++fr) {
      int row = wr*64 + fr*16 + lrow;
      afrag[fr] = *reinterpret_cast<const bf16x8*>(&Alds[row][lk*8]);
    }
    #pragma unroll
    for (int fr = 0; fr < 4; ++fr)
      #pragma unroll
      for (int fc = 0; fc < 4; ++fc)
        acc[fr][fc] = __builtin_amdgcn_mfma_f32_16x16x32_bf16(
            afrag[fr], bfrag[fc], acc[fr][fc], 0, 0, 0);
    __syncthreads();
    #pragma unroll
    for (int fc = 0; fc < 4; ++fc) bfrag[fc] = bnext[fc];
  }

  // epilogue: D mapping col=lane&15, row=(lane>>4)*4+i  (verified m89/m91)
  #pragma unroll
  for (int fr = 0; fr < 4; ++fr) {
    int mrow = m0 + wr*64 + fr*16 + lk*4;
    #pragma unroll
    for (int fc = 0; fc < 4; ++fc) {
      int col = n0 + wc*64 + fc*16 + lrow;
      float bb = bias[col];
      #pragma unroll
      for (int i = 0; i < 4; ++i)
        tokens[(size_t)(mrow + i)*PROJ + col] = acc[fr][fc][i] + bb;
    }
  }
}

extern "C" void kernel_launch(void* const* d_in, const int* in_sizes, int n_in,
                              void* d_out, int out_size, void* d_ws, size_t ws_size,
                              hipStream_t stream) {
  const float* images = (const float*)d_in[0];
  const float* gamma  = (const float*)d_in[1];
  const float* beta   = (const float*)d_in[2];
  const float* W      = (const float*)d_in[3];
  const float* bias   = (const float*)d_in[4];
  float* tokens  = (float*)d_out;
  float* patches = (float*)d_out + TOK_SIZE;

  float2* mr = (float2*)d_ws;                                  // 12544 * 8B
  unsigned short* Wt = (unsigned short*)((char*)d_ws + (1 << 20)); // 768x3840 bf16

  prep_kernel<<<M_TOT, 256, 0, stream>>>(images, patches, mr);
  wtrans_kernel<<<dim3(24, 120), dim3(32, 8), 0, stream>>>(W, Wt);
  gemm_kernel<<<dim3(6, 98), 256, 0, stream>>>(patches, mr, gamma, beta, Wt, bias, tokens);
}

// Round 2
// 248.080 us; speedup vs baseline: 1.7772x; 1.7772x over previous
//
#include <hip/hip_runtime.h>
#include <hip/hip_bf16.h>

#define IMG 224
#define NPS 14
#define NP  196
#define BATCH 64
#define PD  3840
#define PROJ 768
#define M_TOT (BATCH*NP)        // 12544
#define TOK_SIZE (M_TOT*PROJ)   // 9633792
#define KT  120                 // PD/32
#define MT  98                  // M_TOT/128
#define NT  6                   // PROJ/128
#define TILE_BYTES 8192         // 128*32*2

typedef __attribute__((ext_vector_type(8))) __bf16 bf16x8;
typedef __attribute__((ext_vector_type(4))) float f32x4;

__device__ __forceinline__ unsigned short f2bf(float f) {
    unsigned int u = __builtin_bit_cast(unsigned int, f);
    u += 0x7FFFu + ((u >> 16) & 1u);
    return (unsigned short)(u >> 16);
}

#define GLD16(gsrc, ldst) __builtin_amdgcn_global_load_lds( \
    (const __attribute__((address_space(1))) unsigned int*)(gsrc), \
    (__attribute__((address_space(3))) unsigned int*)(ldst), 16, 0, 0)

// ============== FAST PATH ==============

// prep2: gather + mean/rstd + write patches f32 + normed bf16 A (tiled+swizzled)
__global__ __launch_bounds__(512) void prep2_kernel(
    const float* __restrict__ images, const float* __restrict__ gamma,
    const float* __restrict__ beta, float* __restrict__ patches_out,
    char* __restrict__ Aws) {
  const int pid = blockIdx.x;
  const int b  = pid / NP;
  const int pp = pid - b*NP;
  const int ph = pp / NPS;
  const int pw = pp - ph*NPS;
  const int t = threadIdx.x;
  const int d0 = t * 8;

  float v[8];
  float s = 0.f, s2 = 0.f;
  if (t < 480) {
    #pragma unroll
    for (int e = 0; e < 8; ++e) {
      int d = d0 + e;
      int rem = d / 15;
      int ch5 = d - rem*15;
      int q = rem & 15, p = rem >> 4;
      int g = ch5 / 3;
      int c = ch5 - g*3;
      int dh = (g==0) ? 0 : ((g & 1) ? 8 : -8);
      int dw = (g==0) ? 0 : ((g <= 2) ? 8 : -8);
      int ii = ph*16 + p + dh;
      int jj = pw*16 + q + dw;
      float val = 0.f;
      if ((unsigned)ii < IMG && (unsigned)jj < IMG)
        val = images[((b*IMG + ii)*IMG + jj)*3 + c];
      v[e] = val; s += val; s2 += val*val;
    }
  } else {
    #pragma unroll
    for (int e = 0; e < 8; ++e) v[e] = 0.f;
  }

  #pragma unroll
  for (int o = 32; o > 0; o >>= 1) { s += __shfl_xor(s, o); s2 += __shfl_xor(s2, o); }
  __shared__ float red[16];
  __shared__ float mstat[2];
  if ((t & 63) == 0) { red[(t>>6)*2] = s; red[(t>>6)*2+1] = s2; }
  __syncthreads();
  if (t == 0) {
    float S = 0.f, S2 = 0.f;
    #pragma unroll
    for (int i = 0; i < 8; ++i) { S += red[i*2]; S2 += red[i*2+1]; }
    float mean = S * (1.f/PD);
    float var  = S2 * (1.f/PD) - mean*mean;
    mstat[0] = mean;
    mstat[1] = rsqrtf(var + 1e-6f);
  }
  __syncthreads();
  const float mean = mstat[0], rstd = mstat[1];

  if (t < 480) {
    float4* po = (float4*)(patches_out + (size_t)pid*PD + d0);
    po[0] = make_float4(v[0], v[1], v[2], v[3]);
    po[1] = make_float4(v[4], v[5], v[6], v[7]);

    const float4 g0 = *(const float4*)(gamma + d0);
    const float4 g1 = *(const float4*)(gamma + d0 + 4);
    const float4 b0 = *(const float4*)(beta + d0);
    const float4 b1 = *(const float4*)(beta + d0 + 4);
    unsigned int u0 = (unsigned)f2bf((v[0]-mean)*rstd*g0.x + b0.x)
                    | ((unsigned)f2bf((v[1]-mean)*rstd*g0.y + b0.y) << 16);
    unsigned int u1 = (unsigned)f2bf((v[2]-mean)*rstd*g0.z + b0.z)
                    | ((unsigned)f2bf((v[3]-mean)*rstd*g0.w + b0.w) << 16);
    unsigned int u2 = (unsigned)f2bf((v[4]-mean)*rstd*g1.x + b1.x)
                    | ((unsigned)f2bf((v[5]-mean)*rstd*g1.y + b1.y) << 16);
    unsigned int u3 = (unsigned)f2bf((v[6]-mean)*rstd*g1.z + b1.z)
                    | ((unsigned)f2bf((v[7]-mean)*rstd*g1.w + b1.w) << 16);

    const int mtile = pid >> 7, mrow = pid & 127;
    const int ktile = t >> 2;
    const int kk8   = (t & 3) * 8;
    const int byteoff = (mrow*64 + kk8*2) ^ ((mrow & 7) << 4);
    *(uint4*)(Aws + ((size_t)(mtile*KT + ktile))*TILE_BYTES + byteoff) =
        make_uint4(u0, u1, u2, u3);
  }
}

// wtrans2: W (3840x768 f32) -> tiled+swizzled bf16 [ntile][ktile][128x32]
__global__ __launch_bounds__(256) void wtrans2_kernel(
    const float* __restrict__ W, char* __restrict__ Bws) {
  __shared__ float tile[32][33];
  const int bx = blockIdx.x;   // n-tile/32: 0..23
  const int by = blockIdx.y;   // k-tile/32: 0..119
  const int tid = threadIdx.x;
  const int nl = tid & 31;
  #pragma unroll
  for (int r = 0; r < 4; ++r) {
    int kl = (tid >> 5) + r*8;
    tile[nl][kl] = W[(by*32 + kl)*PROJ + bx*32 + nl];
  }
  __syncthreads();
  if (tid < 128) {
    const int n_local = tid >> 2;
    const int kchunk  = tid & 3;
    unsigned int u[4];
    #pragma unroll
    for (int j = 0; j < 4; ++j) {
      unsigned short lo = f2bf(tile[n_local][kchunk*8 + j*2]);
      unsigned short hi = f2bf(tile[n_local][kchunk*8 + j*2 + 1]);
      u[j] = (unsigned)lo | ((unsigned)hi << 16);
    }
    const int n = bx*32 + n_local;
    const int ntile = n >> 7, nrow = n & 127;
    const int kk8 = kchunk * 8;
    const int byteoff = (nrow*64 + kk8*2) ^ ((nrow & 7) << 4);
    *(uint4*)(Bws + ((size_t)(ntile*KT + by))*TILE_BYTES + byteoff) =
        make_uint4(u[0], u[1], u[2], u[3]);
  }
}

// gemm2: tokens = A @ B^T + bias   (A,B pre-normalized bf16, tiled+swizzled)
__global__ __launch_bounds__(256) void gemm2_kernel(
    const char* __restrict__ Aws, const char* __restrict__ Bws,
    const float* __restrict__ bias, float* __restrict__ tokens) {
  __shared__ __align__(16) char lds[2*TILE_BYTES];
  const int bn = blockIdx.x;   // 0..5
  const int bm = blockIdx.y;   // 0..97
  const int t = threadIdx.x;
  const int l = t & 63;
  const int w = t >> 6;
  const int wr = w >> 1, wc = w & 1;
  const int lrow = l & 15;
  const int lk   = l >> 4;

  const char* Ag = Aws + (size_t)bm*KT*TILE_BYTES;
  const char* Bg = Bws + (size_t)bn*KT*TILE_BYTES;
  char* ldsA0 = &lds[(2*w + 0)*1024];
  char* ldsA1 = &lds[(2*w + 1)*1024];
  char* ldsB0 = &lds[TILE_BYTES + (2*w + 0)*1024];
  char* ldsB1 = &lds[TILE_BYTES + (2*w + 1)*1024];
  const int ga0 = (2*w + 0)*1024 + l*16;
  const int ga1 = (2*w + 1)*1024 + l*16;

  int aoff[4], boff[4];
  #pragma unroll
  for (int fr = 0; fr < 4; ++fr) {
    int row = wr*64 + fr*16 + lrow;
    aoff[fr] = (row*64 + lk*16) ^ ((row & 7) << 4);
  }
  #pragma unroll
  for (int fc = 0; fc < 4; ++fc) {
    int row = wc*64 + fc*16 + lrow;
    boff[fc] = TILE_BYTES + ((row*64 + lk*16) ^ ((row & 7) << 4));
  }

  f32x4 acc[4][4];
  #pragma unroll
  for (int i = 0; i < 4; ++i)
    #pragma unroll
    for (int j = 0; j < 4; ++j) acc[i][j] = f32x4{0.f, 0.f, 0.f, 0.f};

  for (int kt = 0; kt < KT; ++kt) {
    const size_t off = (size_t)kt * TILE_BYTES;
    GLD16(Ag + off + ga0, ldsA0);
    GLD16(Ag + off + ga1, ldsA1);
    GLD16(Bg + off + ga0, ldsB0);
    GLD16(Bg + off + ga1, ldsB1);
    __syncthreads();
    bf16x8 af[4], bf[4];
    #pragma unroll
    for (int fr = 0; fr < 4; ++fr) af[fr] = *(const bf16x8*)(lds + aoff[fr]);
    #pragma unroll
    for (int fc = 0; fc < 4; ++fc) bf[fc] = *(const bf16x8*)(lds + boff[fc]);
    #pragma unroll
    for (int fr = 0; fr < 4; ++fr)
      #pragma unroll
      for (int fc = 0; fc < 4; ++fc)
        acc[fr][fc] = __builtin_amdgcn_mfma_f32_16x16x32_bf16(
            af[fr], bf[fc], acc[fr][fc], 0, 0, 0);
    __syncthreads();
  }

  const int m0 = bm * 128, n0 = bn * 128;
  #pragma unroll
  for (int fr = 0; fr < 4; ++fr) {
    int mrow = m0 + wr*64 + fr*16 + lk*4;
    #pragma unroll
    for (int fc = 0; fc < 4; ++fc) {
      int col = n0 + wc*64 + fc*16 + lrow;
      float bb = bias[col];
      #pragma unroll
      for (int i = 0; i < 4; ++i)
        tokens[(size_t)(mrow + i)*PROJ + col] = acc[fr][fc][i] + bb;
    }
  }
}

// ============== FALLBACK PATH (round-1, known-passing) ==============

__global__ __launch_bounds__(256) void prep_kernel(
    const float* __restrict__ images, float* __restrict__ patches_out,
    float2* __restrict__ mr) {
  const int pid = blockIdx.x;
  const int b  = pid / NP;
  const int pp = pid - b*NP;
  const int ph = pp / NPS;
  const int pw = pp - ph*NPS;
  const int t = threadIdx.x;
  float s = 0.f, s2 = 0.f;
  #pragma unroll
  for (int r = 0; r < 15; ++r) {
    int d   = t + r*256;
    int ch5 = d % 15;
    int rem = d / 15;
    int q = rem & 15;
    int p = rem >> 4;
    int g = ch5 / 3;
    int c = ch5 - g*3;
    int dh = (g==0) ? 0 : ((g & 1) ? 8 : -8);
    int dw = (g==0) ? 0 : ((g <= 2) ? 8 : -8);
    int ii = ph*16 + p + dh;
    int jj = pw*16 + q + dw;
    float v = 0.f;
    if ((unsigned)ii < IMG && (unsigned)jj < IMG)
      v = images[((b*IMG + ii)*IMG + jj)*3 + c];
    s += v; s2 += v*v;
    patches_out[(size_t)pid*PD + d] = v;
  }
  #pragma unroll
  for (int o = 32; o > 0; o >>= 1) { s += __shfl_xor(s, o); s2 += __shfl_xor(s2, o); }
  __shared__ float red[8];
  int w = t >> 6;
  if ((t & 63) == 0) { red[w*2] = s; red[w*2+1] = s2; }
  __syncthreads();
  if (t == 0) {
    float S  = red[0]+red[2]+red[4]+red[6];
    float S2 = red[1]+red[3]+red[5]+red[7];
    float mean = S * (1.f/PD);
    float var  = S2 * (1.f/PD) - mean*mean;
    mr[pid] = make_float2(mean, rsqrtf(var + 1e-6f));
  }
}

__global__ __launch_bounds__(256) void wtrans_kernel(
    const float* __restrict__ W, unsigned short* __restrict__ Wt) {
  __shared__ float tile[32][33];
  const int bx = blockIdx.x;
  const int by = blockIdx.y;
  const int tx = threadIdx.x & 31;
  const int ty = threadIdx.x >> 5;
  #pragma unroll
  for (int r = 0; r < 4; ++r)
    tile[ty + r*8][tx] = W[(by*32 + ty + r*8)*PROJ + bx*32 + tx];
  __syncthreads();
  #pragma unroll
  for (int r = 0; r < 4; ++r)
    Wt[(size_t)(bx*32 + ty + r*8)*PD + by*32 + tx] = f2bf(tile[tx][ty + r*8]);
}

__global__ __launch_bounds__(256) void gemm_kernel(
    const float* __restrict__ patches, const float2* __restrict__ mr,
    const float* __restrict__ gamma, const float* __restrict__ beta,
    const unsigned short* __restrict__ Wt, const float* __restrict__ bias,
    float* __restrict__ tokens) {
  __shared__ unsigned short Alds[128][40];
  const int bn = blockIdx.x;
  const int bm = blockIdx.y;
  const int t = threadIdx.x;
  const int l = t & 63;
  const int w = t >> 6;
  const int wr = w >> 1, wc = w & 1;
  const int m0 = bm * 128, n0 = bn * 128;
  const int lrow = l & 15, lk = l >> 4;
  const unsigned short* bp[4];
  #pragma unroll
  for (int fc = 0; fc < 4; ++fc)
    bp[fc] = Wt + (size_t)(n0 + wc*64 + fc*16 + lrow) * PD + lk*8;
  const int srow = t >> 3;
  const int skq  = (t & 7) * 4;
  f32x4 acc[4][4];
  #pragma unroll
  for (int i = 0; i < 4; ++i)
    #pragma unroll
    for (int j = 0; j < 4; ++j) acc[i][j] = f32x4{0.f, 0.f, 0.f, 0.f};
  bf16x8 bfrag[4], bnext[4];
  #pragma unroll
  for (int fc = 0; fc < 4; ++fc) bfrag[fc] = *reinterpret_cast<const bf16x8*>(bp[fc]);
  for (int kt = 0; kt < KT; ++kt) {
    const int k0 = kt * 32;
    #pragma unroll
    for (int pass = 0; pass < 4; ++pass) {
      int row = pass*32 + srow;
      int m = m0 + row;
      float2 mrv = mr[m];
      const float4 v  = *reinterpret_cast<const float4*>(patches + (size_t)m*PD + k0 + skq);
      const float4 gv = *reinterpret_cast<const float4*>(gamma + k0 + skq);
      const float4 bv = *reinterpret_cast<const float4*>(beta  + k0 + skq);
      ushort4 o;
      o.x = f2bf((v.x - mrv.x)*mrv.y*gv.x + bv.x);
      o.y = f2bf((v.y - mrv.x)*mrv.y*gv.y + bv.y);
      o.z = f2bf((v.z - mrv.x)*mrv.y*gv.z + bv.z);
      o.w = f2bf((v.w - mrv.x)*mrv.y*gv.w + bv.w);
      *reinterpret_cast<ushort4*>(&Alds[row][skq]) = o;
    }
    if (kt < KT-1) {
      #pragma unroll
      for (int fc = 0; fc < 4; ++fc)
        bnext[fc] = *reinterpret_cast<const bf16x8*>(bp[fc] + k0 + 32);
    }
    __syncthreads();
    bf16x8 afrag[4];
    #pragma unroll
    for (int fr = 0; fr < 4; ++fr)
      afrag[fr] = *reinterpret_cast<const bf16x8*>(&Alds[wr*64 + fr*16 + lrow][lk*8]);
    #pragma unroll
    for (int fr = 0; fr < 4; ++fr)
      #pragma unroll
      for (int fc = 0; fc < 4; ++fc)
        acc[fr][fc] = __builtin_amdgcn_mfma_f32_16x16x32_bf16(
            afrag[fr], bfrag[fc], acc[fr][fc], 0, 0, 0);
    __syncthreads();
    #pragma unroll
    for (int fc = 0; fc < 4; ++fc) bfrag[fc] = bnext[fc];
  }
  #pragma unroll
  for (int fr = 0; fr < 4; ++fr) {
    int mrow = m0 + wr*64 + fr*16 + lk*4;
    #pragma unroll
    for (int fc = 0; fc < 4; ++fc) {
      int col = n0 + wc*64 + fc*16 + lrow;
      float bb = bias[col];
      #pragma unroll
      for (int i = 0; i < 4; ++i)
        tokens[(size_t)(mrow + i)*PROJ + col] = acc[fr][fc][i] + bb;
    }
  }
}

// ============== launcher ==============

extern "C" void kernel_launch(void* const* d_in, const int* in_sizes, int n_in,
                              void* d_out, int out_size, void* d_ws, size_t ws_size,
                              hipStream_t stream) {
  const float* images = (const float*)d_in[0];
  const float* gamma  = (const float*)d_in[1];
  const float* beta   = (const float*)d_in[2];
  const float* W      = (const float*)d_in[3];
  const float* bias   = (const float*)d_in[4];
  float* tokens  = (float*)d_out;
  float* patches = (float*)d_out + TOK_SIZE;

  const size_t WS_A_OFF = 6u << 20;                               // 6 MiB
  const size_t need = WS_A_OFF + (size_t)MT*KT*TILE_BYTES;        // ~98 MiB

  if (ws_size >= need) {
    char* Bws = (char*)d_ws;
    char* Aws = (char*)d_ws + WS_A_OFF;
    prep2_kernel<<<M_TOT, 512, 0, stream>>>(images, gamma, beta, patches, Aws);
    wtrans2_kernel<<<dim3(24, KT), 256, 0, stream>>>(W, Bws);
    gemm2_kernel<<<dim3(NT, MT), 256, 0, stream>>>(Aws, Bws, bias, tokens);
  } else {
    float2* mrp = (float2*)d_ws;
    unsigned short* Wt = (unsigned short*)((char*)d_ws + (1 << 20));
    prep_kernel<<<M_TOT, 256, 0, stream>>>(images, patches, mrp);
    wtrans_kernel<<<dim3(24, KT), 256, 0, stream>>>(W, Wt);
    gemm_kernel<<<dim3(NT, MT), 256, 0, stream>>>(patches, mrp, gamma, beta, Wt, bias, tokens);
  }
}